// Round 1
// baseline (478.565 us; speedup 1.0000x reference)
//
#include <hip/hip_runtime.h>

// Problem constants
constexpr int DMODEL = 1024;
constexpr int NHEAD  = 16;
constexpr int DKH    = 64;
constexpr int BATCH  = 2;
constexpr int SEQ    = 2048;
constexpr int MTOT   = BATCH * SEQ;   // 4096

typedef __attribute__((ext_vector_type(8))) short short8;
typedef __attribute__((ext_vector_type(4))) float floatx4;

// fp32 -> bf16 round-to-nearest-even (finite inputs)
__device__ __forceinline__ ushort f2bf(float f) {
    unsigned u = __builtin_bit_cast(unsigned, f);
    u = (u + 0x7fffu + ((u >> 16) & 1u)) >> 16;
    return (ushort)u;
}

// ---------------------------------------------------------------------------
// GEMM: Y = A @ W^T + bias.  A is [MTOT, DMODEL] (fp32 for MODE 0/1, bf16 for
// MODE 2), W is [DMODEL, DMODEL] fp32 row-major (so both operands read along K
// contiguously -> NT GEMM).
// MODE 0: write bf16 [B,H,S,DKH]   (Q, K)
// MODE 1: write bf16 [B,H,DKH,S]   (V transposed, for PV B-operand)
// MODE 2: write fp32 [MTOT, DMODEL] (final output)
// Tile 128x128, BK=32, 256 threads = 4 waves in 2x2, each wave 64x64 = 4x4
// frags of 16x16x32 bf16 MFMA.
// ---------------------------------------------------------------------------
template <int MODE>
__global__ void gemm_kernel(const void* __restrict__ Av,
                            const float* __restrict__ W,
                            const float* __restrict__ bias,
                            void* __restrict__ Out) {
    constexpr int BM = 128, BN = 128, BK = 32, LDT = BK + 8;  // 80B row stride
    __shared__ ushort Als[BM][LDT];
    __shared__ ushort Bls[BN][LDT];

    const int tid = threadIdx.x;
    const int w = tid >> 6, l = tid & 63;
    const int wm = w >> 1, wn = w & 1;
    const int lr = l & 15, lg = l >> 4;
    const int m0 = blockIdx.x * BM, n0 = blockIdx.y * BN;

    floatx4 acc[4][4] = {};

    for (int k0 = 0; k0 < DMODEL; k0 += BK) {
        __syncthreads();
        {
            const int row = tid >> 3;          // 0..31
            const int c4  = (tid & 7) * 4;     // 0..28
            // stage W tile (always fp32 source)
#pragma unroll
            for (int rr = 0; rr < BM; rr += 32) {
                const float4 v = *(const float4*)(W + (size_t)(n0 + row + rr) * DMODEL + k0 + c4);
                ushort* p = &Bls[row + rr][c4];
                p[0] = f2bf(v.x); p[1] = f2bf(v.y); p[2] = f2bf(v.z); p[3] = f2bf(v.w);
            }
            if constexpr (MODE != 2) {
                const float* A = (const float*)Av;
#pragma unroll
                for (int rr = 0; rr < BM; rr += 32) {
                    const float4 v = *(const float4*)(A + (size_t)(m0 + row + rr) * DMODEL + k0 + c4);
                    ushort* p = &Als[row + rr][c4];
                    p[0] = f2bf(v.x); p[1] = f2bf(v.y); p[2] = f2bf(v.z); p[3] = f2bf(v.w);
                }
            } else {
                const ushort* A = (const ushort*)Av;
                const int row2 = tid >> 2;        // 0..63
                const int c8   = (tid & 3) * 8;   // 0..24
#pragma unroll
                for (int rr = 0; rr < BM; rr += 64) {
                    *(uint4*)&Als[row2 + rr][c8] =
                        *(const uint4*)(A + (size_t)(m0 + row2 + rr) * DMODEL + k0 + c8);
                }
            }
        }
        __syncthreads();

        short8 af[4], bf[4];
#pragma unroll
        for (int i = 0; i < 4; i++)
            af[i] = *(const short8*)&Als[wm * 64 + i * 16 + lr][lg * 8];
#pragma unroll
        for (int j = 0; j < 4; j++)
            bf[j] = *(const short8*)&Bls[wn * 64 + j * 16 + lr][lg * 8];
#pragma unroll
        for (int i = 0; i < 4; i++)
#pragma unroll
            for (int j = 0; j < 4; j++)
                acc[i][j] = __builtin_amdgcn_mfma_f32_16x16x32_bf16(af[i], bf[j], acc[i][j], 0, 0, 0);
    }

    // epilogue: D[row][col], row = (lane>>4)*4 + reg, col = lane&15
#pragma unroll
    for (int i = 0; i < 4; i++) {
#pragma unroll
        for (int j = 0; j < 4; j++) {
#pragma unroll
            for (int p = 0; p < 4; p++) {
                const int rg = m0 + wm * 64 + i * 16 + lg * 4 + p;
                const int cg = n0 + wn * 64 + j * 16 + lr;
                const float v = acc[i][j][p] + bias[cg];
                if constexpr (MODE == 2) {
                    ((float*)Out)[(size_t)rg * DMODEL + cg] = v;
                } else {
                    const int b = rg >> 11, s = rg & (SEQ - 1);
                    const int h = cg >> 6, d = cg & (DKH - 1);
                    ushort* O = (ushort*)Out;
                    if constexpr (MODE == 0)
                        O[((size_t)(b * NHEAD + h) * SEQ + s) * DKH + d] = f2bf(v);
                    else
                        O[((size_t)(b * NHEAD + h) * DKH + d) * SEQ + s] = f2bf(v);
                }
            }
        }
    }
}

// ---------------------------------------------------------------------------
// Flash attention.  Grid: (SEQ/128, BATCH*NHEAD).  Block 256 = 4 waves, each
// wave owns 32 q-rows independently.  K/V tiles (KT=64) staged in LDS with
// XOR swizzle (16B slot ^= row&7) for conflict-free b128 frag reads.
// Online softmax per q-row: reduce over 4 n-frags + __shfl_xor(1,2,4,8)
// within the 16-lane column group.  P transposed via padded per-wave LDS.
// ---------------------------------------------------------------------------
__global__ void attn_kernel(const ushort* __restrict__ Q,
                            const ushort* __restrict__ K,
                            const ushort* __restrict__ Vt,
                            ushort* __restrict__ O) {
    constexpr int QT = 128, KT = 64;
    __shared__ ushort Kls[KT][DKH];       // [kpos][d], swizzled
    __shared__ ushort Vls[DKH][KT];       // [d][kpos], swizzled
    __shared__ ushort Pls[4][32][72];     // per-wave P transpose buffer (144B rows)

    const int tid = threadIdx.x;
    const int w = tid >> 6, l = tid & 63;
    const int lr = l & 15, lg = l >> 4;
    const int bh = blockIdx.y;
    const int q0 = blockIdx.x * QT;
    const ushort* Qh = Q  + (size_t)bh * SEQ * DKH;
    const ushort* Kh = K  + (size_t)bh * SEQ * DKH;
    const ushort* Vh = Vt + (size_t)bh * DKH * SEQ;

    // Q fragments live in registers for the whole kernel
    short8 qf[2][2];
#pragma unroll
    for (int i = 0; i < 2; i++)
#pragma unroll
        for (int kk = 0; kk < 2; kk++)
            qf[i][kk] = *(const short8*)(Qh + (size_t)(q0 + w * 32 + i * 16 + lr) * DKH + kk * 32 + lg * 8);

    floatx4 acc[2][4] = {};
    float mrun[2][4], lrun[2][4];
#pragma unroll
    for (int i = 0; i < 2; i++)
#pragma unroll
        for (int p = 0; p < 4; p++) { mrun[i][p] = -3e38f; lrun[i][p] = 0.f; }

    for (int kt = 0; kt < SEQ; kt += KT) {
        __syncthreads();
        {
            const int row = tid >> 3, slot = tid & 7;
#pragma unroll
            for (int rr = 0; rr < 64; rr += 32) {
                const int r = row + rr;
                const int sw = ((slot ^ (r & 7)) * 8);
                *(uint4*)&Kls[r][sw] = *(const uint4*)(Kh + (size_t)(kt + r) * DKH + slot * 8);
                *(uint4*)&Vls[r][sw] = *(const uint4*)(Vh + (size_t)r * SEQ + kt + slot * 8);
            }
        }
        __syncthreads();

        // S = (Q K^T) * scale
        floatx4 sa[2][4] = {};
#pragma unroll
        for (int kk = 0; kk < 2; kk++) {
            short8 kf[4];
#pragma unroll
            for (int n = 0; n < 4; n++) {
                const int r = n * 16 + lr, slot = kk * 4 + lg;
                kf[n] = *(const short8*)&Kls[r][(slot ^ (r & 7)) * 8];
            }
#pragma unroll
            for (int i = 0; i < 2; i++)
#pragma unroll
                for (int n = 0; n < 4; n++)
                    sa[i][n] = __builtin_amdgcn_mfma_f32_16x16x32_bf16(qf[i][kk], kf[n], sa[i][n], 0, 0, 0);
        }

        // online softmax (rows = i*16 + lg*4 + p, cols across n and lane&15)
#pragma unroll
        for (int i = 0; i < 2; i++) {
#pragma unroll
            for (int p = 0; p < 4; p++) {
                float mx = -3e38f;
#pragma unroll
                for (int n = 0; n < 4; n++) { sa[i][n][p] *= 0.125f; mx = fmaxf(mx, sa[i][n][p]); }
                mx = fmaxf(mx, __shfl_xor(mx, 1));
                mx = fmaxf(mx, __shfl_xor(mx, 2));
                mx = fmaxf(mx, __shfl_xor(mx, 4));
                mx = fmaxf(mx, __shfl_xor(mx, 8));
                const float mn = fmaxf(mrun[i][p], mx);
                const float corr = __expf(mrun[i][p] - mn);
                float ps = 0.f;
#pragma unroll
                for (int n = 0; n < 4; n++) {
                    const float e = __expf(sa[i][n][p] - mn);
                    sa[i][n][p] = e;
                    ps += e;
                }
                ps += __shfl_xor(ps, 1);
                ps += __shfl_xor(ps, 2);
                ps += __shfl_xor(ps, 4);
                ps += __shfl_xor(ps, 8);
                lrun[i][p] = lrun[i][p] * corr + ps;
                mrun[i][p] = mn;
#pragma unroll
                for (int n = 0; n < 4; n++) acc[i][n][p] *= corr;
            }
        }

        // P -> bf16, transpose through per-wave LDS
#pragma unroll
        for (int i = 0; i < 2; i++)
#pragma unroll
            for (int n = 0; n < 4; n++)
#pragma unroll
                for (int p = 0; p < 4; p++)
                    Pls[w][i * 16 + lg * 4 + p][n * 16 + lr] = f2bf(sa[i][n][p]);
        __syncthreads();

        // O += P V
#pragma unroll
        for (int kk = 0; kk < 2; kk++) {
            short8 pf[2], vf[4];
#pragma unroll
            for (int i = 0; i < 2; i++)
                pf[i] = *(const short8*)&Pls[w][i * 16 + lr][kk * 32 + lg * 8];
#pragma unroll
            for (int n = 0; n < 4; n++) {
                const int r = n * 16 + lr, slot = kk * 4 + lg;
                vf[n] = *(const short8*)&Vls[r][(slot ^ (r & 7)) * 8];
            }
#pragma unroll
            for (int i = 0; i < 2; i++)
#pragma unroll
                for (int n = 0; n < 4; n++)
                    acc[i][n] = __builtin_amdgcn_mfma_f32_16x16x32_bf16(pf[i], vf[n], acc[i][n], 0, 0, 0);
        }
    }

    // epilogue: O /= l, write [B,S,H*DKH] bf16
    const int b = bh >> 4, h = bh & (NHEAD - 1);
#pragma unroll
    for (int i = 0; i < 2; i++)
#pragma unroll
        for (int n = 0; n < 4; n++)
#pragma unroll
            for (int p = 0; p < 4; p++) {
                const int srow = q0 + w * 32 + i * 16 + lg * 4 + p;
                const int d = n * 16 + lr;
                const float v = acc[i][n][p] / lrun[i][p];
                O[((size_t)(b * SEQ + srow)) * DMODEL + h * DKH + d] = f2bf(v);
            }
}

// ---------------------------------------------------------------------------
extern "C" void kernel_launch(void* const* d_in, const int* in_sizes, int n_in,
                              void* d_out, int out_size, void* d_ws, size_t ws_size,
                              hipStream_t stream) {
    const float* x  = (const float*)d_in[0];
    const float* Wq = (const float*)d_in[1];
    const float* bq = (const float*)d_in[2];
    const float* Wk = (const float*)d_in[3];
    const float* bk = (const float*)d_in[4];
    const float* Wv = (const float*)d_in[5];
    const float* bv = (const float*)d_in[6];
    const float* Wo = (const float*)d_in[7];
    const float* bo = (const float*)d_in[8];

    // workspace: Q, K (bf16 [B,H,S,64]), V^T (bf16 [B,H,64,S]), attn ([4096,1024] bf16)
    ushort* q_ws = (ushort*)d_ws;
    ushort* k_ws = q_ws + (size_t)MTOT * DMODEL;
    ushort* v_ws = k_ws + (size_t)MTOT * DMODEL;
    ushort* a_ws = v_ws + (size_t)MTOT * DMODEL;
    // total ws use: 4 * 8 MiB = 32 MiB

    const dim3 gg(MTOT / 128, DMODEL / 128);
    const dim3 bb(256);
    hipLaunchKernelGGL((gemm_kernel<0>), gg, bb, 0, stream, (const void*)x, Wq, bq, (void*)q_ws);
    hipLaunchKernelGGL((gemm_kernel<0>), gg, bb, 0, stream, (const void*)x, Wk, bk, (void*)k_ws);
    hipLaunchKernelGGL((gemm_kernel<1>), gg, bb, 0, stream, (const void*)x, Wv, bv, (void*)v_ws);
    hipLaunchKernelGGL(attn_kernel, dim3(SEQ / 128, BATCH * NHEAD), bb, 0, stream,
                       q_ws, k_ws, v_ws, a_ws);
    hipLaunchKernelGGL((gemm_kernel<2>), gg, bb, 0, stream, (const void*)a_ws, Wo, bo, d_out);
}

// Round 3
// 194.419 us; speedup vs baseline: 2.4615x; 2.4615x over previous
//
#include <hip/hip_runtime.h>

constexpr int DMODEL = 1024;
constexpr int NHEAD  = 16;
constexpr int DKH    = 64;
constexpr int BATCH  = 2;
constexpr int SEQ    = 2048;
constexpr int MTOT   = BATCH * SEQ;   // 4096

typedef __attribute__((ext_vector_type(8))) short short8;
typedef __attribute__((ext_vector_type(4))) float floatx4;

// fp32 -> bf16 round-to-nearest-even
__device__ __forceinline__ ushort f2bf(float f) {
    unsigned u = __builtin_bit_cast(unsigned, f);
    u = (u + 0x7fffu + ((u >> 16) & 1u)) >> 16;
    return (ushort)u;
}

// async 16B global->LDS (lane writes lds + lane*16)
__device__ __forceinline__ void gld16(const ushort* g, ushort* l) {
    __builtin_amdgcn_global_load_lds(
        (const __attribute__((address_space(1))) void*)g,
        (__attribute__((address_space(3))) void*)l, 16, 0, 0);
}

// ---------------------------------------------------------------------------
// Convert pass: x (fp32[4096,1024]) -> xb bf16; Wq/Wk/Wv -> Wc bf16 [3072,1024];
// Wo -> Wob bf16.  One thread = 4 floats.  Grid 8192 x 256 covers 2M float4.
// ---------------------------------------------------------------------------
__global__ __launch_bounds__(256) void cvt_kernel(
    const float* __restrict__ x,  const float* __restrict__ wq,
    const float* __restrict__ wk, const float* __restrict__ wv,
    const float* __restrict__ wo,
    ushort* __restrict__ xb, ushort* __restrict__ wc, ushort* __restrict__ wob) {
    const int id = blockIdx.x * 256 + threadIdx.x;        // 0 .. 2M-1
    const float* src;
    ushort* dst;
    if (id < (1 << 20)) {
        src = x + (size_t)id * 4;
        dst = xb + (size_t)id * 4;
    } else {
        const int t = id - (1 << 20);
        const int seg = t >> 18;                           // 0..3
        const size_t off = (size_t)(t & 0x3ffff) * 4;
        src = (seg == 0 ? wq : seg == 1 ? wk : seg == 2 ? wv : wo) + off;
        dst = (seg < 3) ? (wc + ((size_t)seg << 20) + off) : (wob + off);
    }
    const float4 v = *(const float4*)src;
    uint2 o;
    o.x = (uint)f2bf(v.x) | ((uint)f2bf(v.y) << 16);
    o.y = (uint)f2bf(v.z) | ((uint)f2bf(v.w) << 16);
    *(uint2*)dst = o;
}

// ---------------------------------------------------------------------------
// bf16 GEMM  Y = A @ W^T + bias.  A [M,1024] bf16, W [N,1024] bf16 (NT: both
// K-contiguous).  BK=64, global_load_lds(16B) staging with XOR-swizzled
// content (swizzle applied on the per-lane GLOBAL source; LDS dest linear),
// ds_read_b128 fragment reads with matching swizzle -> 2-way (free) conflicts.
// BMT: 64-row M-subtiles per block (2 -> 128x128 tile, 1 -> 64x128).
// MODE 0: fused QKV epilogue -> Q,K bf16 [B,H,S,64]; V bf16 [B,H,64,S] (transposed)
// MODE 1: fp32 [M,1024] output (final projection)
// ---------------------------------------------------------------------------
template <int BMT, int MODE>
__global__ __launch_bounds__(256) void gemm_bf16(
    const ushort* __restrict__ A, const ushort* __restrict__ W,
    const float* __restrict__ bias0, const float* __restrict__ bias1,
    const float* __restrict__ bias2,
    ushort* __restrict__ Oq, ushort* __restrict__ Ok, ushort* __restrict__ Ov,
    float* __restrict__ Of) {
    constexpr int BM = 64 * BMT, BN = 128, BK = 64;
    constexpr int MI = 2 * BMT;               // 16-row frags per wave (M)
    constexpr int CA = BM / 8, CT = CA + BN / 8, NISS = CT / 4;
    __shared__ ushort Als[BM * BK];
    __shared__ ushort Bls[BN * BK];

    const int tid = threadIdx.x;
    const int w = tid >> 6, l = tid & 63;
    const int lr = l & 15, lg = l >> 4;
    const int wm = w >> 1, wn = w & 1;
    const int m0 = blockIdx.x * BM, n0 = blockIdx.y * BN;

    floatx4 acc[MI][4] = {};

    for (int k0 = 0; k0 < DMODEL; k0 += BK) {
        __syncthreads();
#pragma unroll
        for (int i = 0; i < NISS; i++) {
            const int c = w * NISS + i;                       // chunk id (1KB)
            const int cc = (c < CA) ? c : c - CA;
            const int row = (cc << 3) + (l >> 3);
            const int gcol = (((l & 7) ^ (row & 7)) << 3);    // pre-swizzled source
            if (c < CA)
                gld16(A + (size_t)(m0 + row) * DMODEL + k0 + gcol, &Als[cc << 9]);
            else
                gld16(W + (size_t)(n0 + row) * DMODEL + k0 + gcol, &Bls[cc << 9]);
        }
        __syncthreads();

#pragma unroll
        for (int kk = 0; kk < 2; kk++) {
            short8 af[MI], bfv[4];
            const int u = kk * 4 + lg;                        // 16B slot wanted
#pragma unroll
            for (int i = 0; i < MI; i++) {
                const int r = wm * (BM / 2) + i * 16 + lr;
                af[i] = *(const short8*)&Als[r * 64 + ((u ^ (r & 7)) << 3)];
            }
#pragma unroll
            for (int j = 0; j < 4; j++) {
                const int r = wn * 64 + j * 16 + lr;
                bfv[j] = *(const short8*)&Bls[r * 64 + ((u ^ (r & 7)) << 3)];
            }
#pragma unroll
            for (int i = 0; i < MI; i++)
#pragma unroll
                for (int j = 0; j < 4; j++)
                    acc[i][j] = __builtin_amdgcn_mfma_f32_16x16x32_bf16(af[i], bfv[j], acc[i][j], 0, 0, 0);
        }
    }

    // epilogue: C row = lg*4+p, col = lr (within 16x16 frag)
#pragma unroll
    for (int i = 0; i < MI; i++) {
        const int rbase = m0 + wm * (BM / 2) + i * 16 + lg * 4;
#pragma unroll
        for (int j = 0; j < 4; j++) {
            const int cg = n0 + wn * 64 + j * 16 + lr;
            if constexpr (MODE == 1) {
                const float bb = bias0[cg];
#pragma unroll
                for (int p = 0; p < 4; p++)
                    Of[(size_t)(rbase + p) * DMODEL + cg] = acc[i][j][p] + bb;
            } else {
                const int sel = cg >> 10, cw = cg & 1023;
                const int h = cw >> 6, d = cw & 63;
                const float bb = (sel == 0 ? bias0 : sel == 1 ? bias1 : bias2)[cw];
                const int b = rbase >> 11, s = rbase & (SEQ - 1);
                if (sel == 2) {
                    // V transposed: pack 4 consecutive s into one 8B store
                    uint2 pk;
                    pk.x = (uint)f2bf(acc[i][j][0] + bb) | ((uint)f2bf(acc[i][j][1] + bb) << 16);
                    pk.y = (uint)f2bf(acc[i][j][2] + bb) | ((uint)f2bf(acc[i][j][3] + bb) << 16);
                    *(uint2*)&Ov[((size_t)(b * NHEAD + h) * DKH + d) * SEQ + s] = pk;
                } else {
                    ushort* O = (sel == 0) ? Oq : Ok;
#pragma unroll
                    for (int p = 0; p < 4; p++)
                        O[((size_t)(b * NHEAD + h) * SEQ + s + p) * DKH + d] = f2bf(acc[i][j][p] + bb);
                }
            }
        }
    }
}

// ---------------------------------------------------------------------------
// Flash attention.  Grid (SEQ/128, B*H), 512 threads = 8 waves, each wave owns
// 16 q-rows.  K/V tiles (KT=64) XOR-swizzled in LDS.  Softmax in exp2 domain,
// wave-parallel reduce over the 16-lane column group.  P transposed through
// per-wave LDS with 68-ushort stride (conflict-free scatter).
// ---------------------------------------------------------------------------
__global__ __launch_bounds__(512) void attn_kernel(
    const ushort* __restrict__ Q, const ushort* __restrict__ K,
    const ushort* __restrict__ Vt, ushort* __restrict__ O) {
    constexpr int QT = 128, KT = 64;
    constexpr float SCL = 0.18033688011112042f;   // 0.125 * log2(e)
    __shared__ ushort Kls[KT * 64];      // [kpos][d], swizzled 16B slots
    __shared__ ushort Vls[64 * KT];      // [d][kpos], swizzled 16B slots
    __shared__ ushort Pls[8][16][68];    // per-wave P^T buffer

    const int tid = threadIdx.x;
    const int w = tid >> 6, l = tid & 63;
    const int lr = l & 15, lg = l >> 4;
    const int bh = blockIdx.y;
    const int q0 = blockIdx.x * QT;
    const ushort* Qh = Q  + (size_t)bh * SEQ * DKH;
    const ushort* Kh = K  + (size_t)bh * SEQ * DKH;
    const ushort* Vh = Vt + (size_t)bh * DKH * SEQ;

    short8 qf[2];
#pragma unroll
    for (int kk = 0; kk < 2; kk++)
        qf[kk] = *(const short8*)(Qh + (size_t)(q0 + w * 16 + lr) * DKH + kk * 32 + lg * 8);

    floatx4 acc[4] = {};
    float mrun[4], lrun[4];
#pragma unroll
    for (int p = 0; p < 4; p++) { mrun[p] = -3e38f; lrun[p] = 0.f; }

    const int srow = tid >> 3, sslot = tid & 7;
    const int ssw = ((sslot ^ (srow & 7)) << 3);

    for (int kt = 0; kt < SEQ; kt += KT) {
        __syncthreads();
        *(uint4*)&Kls[srow * 64 + ssw] = *(const uint4*)(Kh + (size_t)(kt + srow) * DKH + sslot * 8);
        *(uint4*)&Vls[srow * 64 + ssw] = *(const uint4*)(Vh + (size_t)srow * SEQ + kt + sslot * 8);
        __syncthreads();

        // S = Q K^T (exp2-domain scale folded later)
        floatx4 sa[4] = {};
#pragma unroll
        for (int kk = 0; kk < 2; kk++) {
            const int u = kk * 4 + lg;
            short8 kf[4];
#pragma unroll
            for (int n = 0; n < 4; n++) {
                const int r = n * 16 + lr;
                kf[n] = *(const short8*)&Kls[r * 64 + ((u ^ (r & 7)) << 3)];
            }
#pragma unroll
            for (int n = 0; n < 4; n++)
                sa[n] = __builtin_amdgcn_mfma_f32_16x16x32_bf16(qf[kk], kf[n], sa[n], 0, 0, 0);
        }

        // online softmax, exp2 domain
#pragma unroll
        for (int p = 0; p < 4; p++) {
            float mx = -3e38f;
#pragma unroll
            for (int n = 0; n < 4; n++) { sa[n][p] *= SCL; mx = fmaxf(mx, sa[n][p]); }
            mx = fmaxf(mx, __shfl_xor(mx, 1));
            mx = fmaxf(mx, __shfl_xor(mx, 2));
            mx = fmaxf(mx, __shfl_xor(mx, 4));
            mx = fmaxf(mx, __shfl_xor(mx, 8));
            const float mn = fmaxf(mrun[p], mx);
            const float corr = exp2f(mrun[p] - mn);
            float ps = 0.f;
#pragma unroll
            for (int n = 0; n < 4; n++) {
                const float e = exp2f(sa[n][p] - mn);
                sa[n][p] = e;
                ps += e;
            }
            ps += __shfl_xor(ps, 1);
            ps += __shfl_xor(ps, 2);
            ps += __shfl_xor(ps, 4);
            ps += __shfl_xor(ps, 8);
            lrun[p] = lrun[p] * corr + ps;
            mrun[p] = mn;
#pragma unroll
            for (int n = 0; n < 4; n++) acc[n][p] *= corr;
        }

        // P -> bf16 transpose through per-wave LDS (no block barrier needed)
#pragma unroll
        for (int n = 0; n < 4; n++)
#pragma unroll
            for (int p = 0; p < 4; p++)
                Pls[w][lg * 4 + p][n * 16 + lr] = f2bf(sa[n][p]);

        // O += P V
#pragma unroll
        for (int kk = 0; kk < 2; kk++) {
            const int u = kk * 4 + lg;
            const short8 pf = *(const short8*)&Pls[w][lr][kk * 32 + lg * 8];
            short8 vf[4];
#pragma unroll
            for (int n = 0; n < 4; n++) {
                const int r = n * 16 + lr;
                vf[n] = *(const short8*)&Vls[r * 64 + ((u ^ (r & 7)) << 3)];
            }
#pragma unroll
            for (int n = 0; n < 4; n++)
                acc[n] = __builtin_amdgcn_mfma_f32_16x16x32_bf16(pf, vf[n], acc[n], 0, 0, 0);
        }
    }

    // epilogue: write [B,S,H*64] bf16
    const int b = bh >> 4, h = bh & (NHEAD - 1);
#pragma unroll
    for (int n = 0; n < 4; n++)
#pragma unroll
        for (int p = 0; p < 4; p++) {
            const int sr = q0 + w * 16 + lg * 4 + p;
            const int d = n * 16 + lr;
            O[((size_t)(b * SEQ + sr)) * DMODEL + h * DKH + d] = f2bf(acc[n][p] / lrun[p]);
        }
}

// ---------------------------------------------------------------------------
extern "C" void kernel_launch(void* const* d_in, const int* in_sizes, int n_in,
                              void* d_out, int out_size, void* d_ws, size_t ws_size,
                              hipStream_t stream) {
    const float* x  = (const float*)d_in[0];
    const float* Wq = (const float*)d_in[1];
    const float* bq = (const float*)d_in[2];
    const float* Wk = (const float*)d_in[3];
    const float* bk = (const float*)d_in[4];
    const float* Wv = (const float*)d_in[5];
    const float* bv = (const float*)d_in[6];
    const float* Wo = (const float*)d_in[7];
    const float* bo = (const float*)d_in[8];

    ushort* base = (ushort*)d_ws;
    ushort* xb  = base;                                  // 4M bf16
    ushort* wc  = xb  + (size_t)4 * 1024 * 1024;         // 3M  (Wq|Wk|Wv)
    ushort* wob = wc  + (size_t)3 * 1024 * 1024;         // 1M
    ushort* qws = wob + (size_t)1 * 1024 * 1024;         // 4M  Q [B,H,S,64]
    ushort* kws = qws + (size_t)4 * 1024 * 1024;         // 4M  K [B,H,S,64]
    ushort* vws = kws + (size_t)4 * 1024 * 1024;         // 4M  V^T [B,H,64,S]
    ushort* aws = vws + (size_t)4 * 1024 * 1024;         // 4M  attn out bf16
    // total 24M ushort = 48 MiB

    hipLaunchKernelGGL(cvt_kernel, dim3(8192), dim3(256), 0, stream,
                       x, Wq, Wk, Wv, Wo, xb, wc, wob);

    hipLaunchKernelGGL((gemm_bf16<2, 0>), dim3(MTOT / 128, 3072 / 128), dim3(256), 0, stream,
                       xb, wc, bq, bk, bv, qws, kws, vws, (float*)nullptr);

    hipLaunchKernelGGL(attn_kernel, dim3(SEQ / 128, BATCH * NHEAD), dim3(512), 0, stream,
                       qws, kws, vws, aws);

    hipLaunchKernelGGL((gemm_bf16<1, 1>), dim3(MTOT / 64, DMODEL / 128), dim3(256), 0, stream,
                       aws, wob, bo, (const float*)nullptr, (const float*)nullptr,
                       (ushort*)nullptr, (ushort*)nullptr, (ushort*)nullptr, (float*)d_out);
}

// Round 5
// 156.735 us; speedup vs baseline: 3.0533x; 1.2404x over previous
//
#include <hip/hip_runtime.h>

constexpr int DMODEL = 1024;
constexpr int NHEAD  = 16;
constexpr int DKH    = 64;
constexpr int BATCH  = 2;
constexpr int SEQ    = 2048;
constexpr int MTOT   = BATCH * SEQ;   // 4096
constexpr float SCL  = 0.18033688011112042f;   // (1/sqrt(64)) * log2(e)

typedef __attribute__((ext_vector_type(8))) short short8;
typedef __attribute__((ext_vector_type(4))) float floatx4;

// fp32 -> bf16 round-to-nearest-even
__device__ __forceinline__ ushort f2bf(float f) {
    unsigned u = __builtin_bit_cast(unsigned, f);
    u = (u + 0x7fffu + ((u >> 16) & 1u)) >> 16;
    return (ushort)u;
}

// async 16B global->LDS (HW writes lds_base + lane*16)
__device__ __forceinline__ void gld16(const ushort* g, ushort* l) {
    __builtin_amdgcn_global_load_lds(
        (const __attribute__((address_space(1))) void*)g,
        (__attribute__((address_space(3))) void*)l, 16, 0, 0);
}

// ---------------------------------------------------------------------------
// Convert pass: x -> xb bf16; Wq/Wk/Wv -> wc bf16 [3072,1024]; Wo -> wob bf16.
// ---------------------------------------------------------------------------
__global__ __launch_bounds__(256) void cvt_kernel(
    const float* __restrict__ x,  const float* __restrict__ wq,
    const float* __restrict__ wk, const float* __restrict__ wv,
    const float* __restrict__ wo,
    ushort* __restrict__ xb, ushort* __restrict__ wc, ushort* __restrict__ wob) {
    const int id = blockIdx.x * 256 + threadIdx.x;        // 0 .. 2M-1
    const float* src;
    ushort* dst;
    if (id < (1 << 20)) {
        src = x + (size_t)id * 4;
        dst = xb + (size_t)id * 4;
    } else {
        const int t = id - (1 << 20);
        const int seg = t >> 18;                           // 0..3
        const size_t off = (size_t)(t & 0x3ffff) * 4;
        src = (seg == 0 ? wq : seg == 1 ? wk : seg == 2 ? wv : wo) + off;
        dst = (seg < 3) ? (wc + ((size_t)seg << 20) + off) : (wob + off);
    }
    const float4 v = *(const float4*)src;
    uint2 o;
    o.x = (uint)f2bf(v.x) | ((uint)f2bf(v.y) << 16);
    o.y = (uint)f2bf(v.z) | ((uint)f2bf(v.w) << 16);
    *(uint2*)dst = o;
}

// ---------------------------------------------------------------------------
// bf16 GEMM  Y = A @ W^T + bias (NT).  BK=64, global_load_lds(16B), XOR
// swizzle via pre-swizzled global source.  MODE 0: fused QKV epilogue
// (Q scaled by SCL; V transposed).  MODE 1: fp32 output.
// ---------------------------------------------------------------------------
template <int BMT, int MODE>
__global__ __launch_bounds__(256) void gemm_bf16(
    const ushort* __restrict__ A, const ushort* __restrict__ W,
    const float* __restrict__ bias0, const float* __restrict__ bias1,
    const float* __restrict__ bias2,
    ushort* __restrict__ Oq, ushort* __restrict__ Ok, ushort* __restrict__ Ov,
    float* __restrict__ Of) {
    constexpr int BM = 64 * BMT, BN = 128, BK = 64;
    constexpr int MI = 2 * BMT;
    constexpr int CA = BM / 8, CT = CA + BN / 8, NISS = CT / 4;
    __shared__ ushort Als[BM * BK];
    __shared__ ushort Bls[BN * BK];

    const int tid = threadIdx.x;
    const int w = tid >> 6, l = tid & 63;
    const int lr = l & 15, lg = l >> 4;
    const int wm = w >> 1, wn = w & 1;
    const int m0 = blockIdx.x * BM, n0 = blockIdx.y * BN;

    floatx4 acc[MI][4] = {};

    for (int k0 = 0; k0 < DMODEL; k0 += BK) {
        __syncthreads();
#pragma unroll
        for (int i = 0; i < NISS; i++) {
            const int c = w * NISS + i;
            const int cc = (c < CA) ? c : c - CA;
            const int row = (cc << 3) + (l >> 3);
            const int gcol = (((l & 7) ^ (row & 7)) << 3);
            if (c < CA)
                gld16(A + (size_t)(m0 + row) * DMODEL + k0 + gcol, &Als[cc << 9]);
            else
                gld16(W + (size_t)(n0 + row) * DMODEL + k0 + gcol, &Bls[cc << 9]);
        }
        __syncthreads();

#pragma unroll
        for (int kk = 0; kk < 2; kk++) {
            short8 af[MI], bfv[4];
            const int u = kk * 4 + lg;
#pragma unroll
            for (int i = 0; i < MI; i++) {
                const int r = wm * (BM / 2) + i * 16 + lr;
                af[i] = *(const short8*)&Als[r * 64 + ((u ^ (r & 7)) << 3)];
            }
#pragma unroll
            for (int j = 0; j < 4; j++) {
                const int r = wn * 64 + j * 16 + lr;
                bfv[j] = *(const short8*)&Bls[r * 64 + ((u ^ (r & 7)) << 3)];
            }
#pragma unroll
            for (int i = 0; i < MI; i++)
#pragma unroll
                for (int j = 0; j < 4; j++)
                    acc[i][j] = __builtin_amdgcn_mfma_f32_16x16x32_bf16(af[i], bfv[j], acc[i][j], 0, 0, 0);
        }
    }

#pragma unroll
    for (int i = 0; i < MI; i++) {
        const int rbase = m0 + wm * (BM / 2) + i * 16 + lg * 4;
#pragma unroll
        for (int j = 0; j < 4; j++) {
            const int cg = n0 + wn * 64 + j * 16 + lr;
            if constexpr (MODE == 1) {
                const float bb = bias0[cg];
#pragma unroll
                for (int p = 0; p < 4; p++)
                    Of[(size_t)(rbase + p) * DMODEL + cg] = acc[i][j][p] + bb;
            } else {
                const int sel = cg >> 10, cw = cg & 1023;
                const int h = cw >> 6, d = cw & 63;
                const float bb = (sel == 0 ? bias0 : sel == 1 ? bias1 : bias2)[cw];
                const int b = rbase >> 11, s = rbase & (SEQ - 1);
                if (sel == 2) {
                    uint2 pk;
                    pk.x = (uint)f2bf(acc[i][j][0] + bb) | ((uint)f2bf(acc[i][j][1] + bb) << 16);
                    pk.y = (uint)f2bf(acc[i][j][2] + bb) | ((uint)f2bf(acc[i][j][3] + bb) << 16);
                    *(uint2*)&Ov[((size_t)(b * NHEAD + h) * DKH + d) * SEQ + s] = pk;
                } else if (sel == 0) {
#pragma unroll
                    for (int p = 0; p < 4; p++)
                        Oq[((size_t)(b * NHEAD + h) * SEQ + s + p) * DKH + d] =
                            f2bf((acc[i][j][p] + bb) * SCL);   // fold softmax scale into Q
                } else {
#pragma unroll
                    for (int p = 0; p < 4; p++)
                        Ok[((size_t)(b * NHEAD + h) * SEQ + s + p) * DKH + d] = f2bf(acc[i][j][p] + bb);
                }
            }
        }
    }
}

// ---------------------------------------------------------------------------
// Flash attention, swapped QK^T (S^T = K·Q^T -> scores for one q-row are
// lane-local across 4 lanes), in-lane softmax, always-rescale.  Single-buffer
// LDS staging via global_load_lds in the proven barrier;STAGE;barrier;COMPUTE
// shape.  Grid (SEQ/128, B*H), 512 threads = 8 waves, wave owns 16 q-rows.
// ---------------------------------------------------------------------------
__global__ __launch_bounds__(512) void attn_kernel(
    const ushort* __restrict__ Q, const ushort* __restrict__ K,
    const ushort* __restrict__ Vt, ushort* __restrict__ O) {
    constexpr int KT = 64;
    __shared__ ushort Kls[KT * 64];      // [kpos][d], swizzled 16B slots
    __shared__ ushort Vls[64 * KT];      // [d][kpos], swizzled 16B slots
    __shared__ ushort Pls[8][16][68];    // per-wave P [q][k] buffer

    const int tid = threadIdx.x;
    const int w = tid >> 6, l = tid & 63;
    const int lr = l & 15, lg = l >> 4;
    const int lg4 = lg * 4;
    const int bh = blockIdx.y;
    const int q0 = blockIdx.x * 128;
    const ushort* Qh = Q  + (size_t)bh * SEQ * DKH;
    const ushort* Kh = K  + (size_t)bh * SEQ * DKH;
    const ushort* Vh = Vt + (size_t)bh * DKH * SEQ;

    // Q fragments (B-operand of swapped QK^T): col = q = lr
    short8 qf[2];
#pragma unroll
    for (int kk = 0; kk < 2; kk++)
        qf[kk] = *(const short8*)(Qh + (size_t)(q0 + w * 16 + lr) * DKH + kk * 32 + lg * 8);

    // staging: wave w stages rows w*8..w*8+7; per-lane global col pre-swizzled
    const int srow = w * 8 + (l >> 3);
    const int scol = ((l & 7) ^ ((l >> 3) & 7)) * 8;
    const ushort* Kg = Kh + (size_t)srow * DKH + scol;
    const ushort* Vg = Vh + (size_t)srow * SEQ + scol;

    floatx4 acc[4] = {};
    float mrun = -3e38f, lrun = 0.f;

    for (int kt = 0; kt < SEQ; kt += KT) {
        __syncthreads();                       // all waves done reading prev tile
        gld16(Kg + (size_t)kt * DKH, Kls + w * 512);
        gld16(Vg + kt, Vls + w * 512);
        __syncthreads();                       // drains vmcnt -> tile ready

        // S^T = K Q^T : lane holds S[q=lr][k = n*16 + lg4 + p]
        floatx4 sa[4] = {};
#pragma unroll
        for (int kk = 0; kk < 2; kk++) {
            const int u = kk * 4 + lg;
#pragma unroll
            for (int n = 0; n < 4; n++) {
                const int r = n * 16 + lr;
                const short8 kf = *(const short8*)&Kls[r * 64 + ((u ^ (r & 7)) << 3)];
                sa[n] = __builtin_amdgcn_mfma_f32_16x16x32_bf16(kf, qf[kk], sa[n], 0, 0, 0);
            }
        }

        // in-lane softmax (always rescale); exp2 domain (scale folded into Q)
        float mx = fmaxf(fmaxf(fmaxf(sa[0][0], sa[0][1]), fmaxf(sa[0][2], sa[0][3])),
                         fmaxf(fmaxf(sa[1][0], sa[1][1]), fmaxf(sa[1][2], sa[1][3])));
        mx = fmaxf(mx, fmaxf(fmaxf(fmaxf(sa[2][0], sa[2][1]), fmaxf(sa[2][2], sa[2][3])),
                             fmaxf(fmaxf(sa[3][0], sa[3][1]), fmaxf(sa[3][2], sa[3][3]))));
        mx = fmaxf(mx, __shfl_xor(mx, 16));
        mx = fmaxf(mx, __shfl_xor(mx, 32));
        const float mn = fmaxf(mrun, mx);
        const float corr = exp2f(mrun - mn);
        mrun = mn;
        lrun *= corr;
#pragma unroll
        for (int p = 0; p < 4; p++) {
            const float cp = __shfl(corr, lg4 + p);
#pragma unroll
            for (int n = 0; n < 4; n++) acc[n][p] *= cp;
        }
        float ps = 0.f;
#pragma unroll
        for (int n = 0; n < 4; n++)
#pragma unroll
            for (int p = 0; p < 4; p++) {
                const float e = exp2f(sa[n][p] - mn);
                sa[n][p] = e;
                ps += e;
            }
        ps += __shfl_xor(ps, 16);
        ps += __shfl_xor(ps, 32);
        lrun += ps;

        // P -> bf16, packed 8B writes into per-wave [q][k] buffer
#pragma unroll
        for (int n = 0; n < 4; n++) {
            uint2 pk;
            pk.x = (uint)f2bf(sa[n][0]) | ((uint)f2bf(sa[n][1]) << 16);
            pk.y = (uint)f2bf(sa[n][2]) | ((uint)f2bf(sa[n][3]) << 16);
            *(uint2*)&Pls[w][lr][n * 16 + lg4] = pk;
        }

        // O += P V
#pragma unroll
        for (int kk = 0; kk < 2; kk++) {
            const int u = kk * 4 + lg;
            const short8 pf = *(const short8*)&Pls[w][lr][kk * 32 + lg * 8];
#pragma unroll
            for (int n = 0; n < 4; n++) {
                const int r = n * 16 + lr;
                const short8 vf = *(const short8*)&Vls[r * 64 + ((u ^ (r & 7)) << 3)];
                acc[n] = __builtin_amdgcn_mfma_f32_16x16x32_bf16(pf, vf, acc[n], 0, 0, 0);
            }
        }
    }

    // epilogue: O row = q = w*16 + lg4+p, col = h*64 + n*16+lr
    const int b = bh >> 4, h = bh & (NHEAD - 1);
#pragma unroll
    for (int p = 0; p < 4; p++) {
        const float lp = __shfl(lrun, lg4 + p);
        const float inv = 1.0f / lp;
        const int sr = q0 + w * 16 + lg4 + p;
#pragma unroll
        for (int n = 0; n < 4; n++) {
            const int d = n * 16 + lr;
            O[((size_t)(b * SEQ + sr)) * DMODEL + h * DKH + d] = f2bf(acc[n][p] * inv);
        }
    }
}

// ---------------------------------------------------------------------------
extern "C" void kernel_launch(void* const* d_in, const int* in_sizes, int n_in,
                              void* d_out, int out_size, void* d_ws, size_t ws_size,
                              hipStream_t stream) {
    const float* x  = (const float*)d_in[0];
    const float* Wq = (const float*)d_in[1];
    const float* bq = (const float*)d_in[2];
    const float* Wk = (const float*)d_in[3];
    const float* bk = (const float*)d_in[4];
    const float* Wv = (const float*)d_in[5];
    const float* bv = (const float*)d_in[6];
    const float* Wo = (const float*)d_in[7];
    const float* bo = (const float*)d_in[8];

    ushort* base = (ushort*)d_ws;
    ushort* xb  = base;                                  // 4M bf16
    ushort* wc  = xb  + (size_t)4 * 1024 * 1024;         // 3M  (Wq|Wk|Wv)
    ushort* wob = wc  + (size_t)3 * 1024 * 1024;         // 1M
    ushort* qws = wob + (size_t)1 * 1024 * 1024;         // 4M  Q [B,H,S,64] (pre-scaled)
    ushort* kws = qws + (size_t)4 * 1024 * 1024;         // 4M  K [B,H,S,64]
    ushort* vws = kws + (size_t)4 * 1024 * 1024;         // 4M  V^T [B,H,64,S]
    ushort* aws = vws + (size_t)4 * 1024 * 1024;         // 4M  attn out bf16

    hipLaunchKernelGGL(cvt_kernel, dim3(8192), dim3(256), 0, stream,
                       x, Wq, Wk, Wv, Wo, xb, wc, wob);

    hipLaunchKernelGGL((gemm_bf16<2, 0>), dim3(MTOT / 128, 3072 / 128), dim3(256), 0, stream,
                       xb, wc, bq, bk, bv, qws, kws, vws, (float*)nullptr);

    hipLaunchKernelGGL(attn_kernel, dim3(SEQ / 128, BATCH * NHEAD), dim3(512), 0, stream,
                       qws, kws, vws, aws);

    hipLaunchKernelGGL((gemm_bf16<1, 1>), dim3(MTOT / 64, DMODEL / 128), dim3(256), 0, stream,
                       aws, wob, bo, (const float*)nullptr, (const float*)nullptr,
                       (ushort*)nullptr, (ushort*)nullptr, (ushort*)nullptr, (float*)d_out);
}

// Round 7
// 149.583 us; speedup vs baseline: 3.1993x; 1.0478x over previous
//
#include <hip/hip_runtime.h>

constexpr int DMODEL = 1024;
constexpr int NHEAD  = 16;
constexpr int DKH    = 64;
constexpr int BATCH  = 2;
constexpr int SEQ    = 2048;
constexpr int MTOT   = BATCH * SEQ;   // 4096
constexpr float SCL  = 0.18033688011112042f;   // (1/sqrt(64)) * log2(e)

typedef __attribute__((ext_vector_type(8))) short short8;
typedef __attribute__((ext_vector_type(4))) float floatx4;

// fp32 -> bf16 round-to-nearest-even
__device__ __forceinline__ ushort f2bf(float f) {
    unsigned u = __builtin_bit_cast(unsigned, f);
    u = (u + 0x7fffu + ((u >> 16) & 1u)) >> 16;
    return (ushort)u;
}

// async 16B global->LDS (HW writes lds_base + lane*16)
__device__ __forceinline__ void gld16(const ushort* g, ushort* l) {
    __builtin_amdgcn_global_load_lds(
        (const __attribute__((address_space(1))) void*)g,
        (__attribute__((address_space(3))) void*)l, 16, 0, 0);
}

// ---------------------------------------------------------------------------
// Convert pass: x -> xb bf16; Wq/Wk/Wv -> wc bf16 [3072,1024]; Wo -> wob bf16.
// ---------------------------------------------------------------------------
__global__ __launch_bounds__(256) void cvt_kernel(
    const float* __restrict__ x,  const float* __restrict__ wq,
    const float* __restrict__ wk, const float* __restrict__ wv,
    const float* __restrict__ wo,
    ushort* __restrict__ xb, ushort* __restrict__ wc, ushort* __restrict__ wob) {
    const int id = blockIdx.x * 256 + threadIdx.x;        // 0 .. 2M-1
    const float* src;
    ushort* dst;
    if (id < (1 << 20)) {
        src = x + (size_t)id * 4;
        dst = xb + (size_t)id * 4;
    } else {
        const int t = id - (1 << 20);
        const int seg = t >> 18;                           // 0..3
        const size_t off = (size_t)(t & 0x3ffff) * 4;
        src = (seg == 0 ? wq : seg == 1 ? wk : seg == 2 ? wv : wo) + off;
        dst = (seg < 3) ? (wc + ((size_t)seg << 20) + off) : (wob + off);
    }
    const float4 v = *(const float4*)src;
    uint2 o;
    o.x = (uint)f2bf(v.x) | ((uint)f2bf(v.y) << 16);
    o.y = (uint)f2bf(v.z) | ((uint)f2bf(v.w) << 16);
    *(uint2*)dst = o;
}

// ---------------------------------------------------------------------------
// bf16 GEMM  Y = A @ W^T + bias (NT).  BK=64, global_load_lds(16B), XOR
// swizzle via pre-swizzled global source.  MODE 0: fused QKV epilogue
// (Q scaled by SCL; V transposed).  MODE 1: fp32 output.
// ---------------------------------------------------------------------------
template <int BMT, int MODE>
__global__ __launch_bounds__(256) void gemm_bf16(
    const ushort* __restrict__ A, const ushort* __restrict__ W,
    const float* __restrict__ bias0, const float* __restrict__ bias1,
    const float* __restrict__ bias2,
    ushort* __restrict__ Oq, ushort* __restrict__ Ok, ushort* __restrict__ Ov,
    float* __restrict__ Of) {
    constexpr int BM = 64 * BMT, BN = 128, BK = 64;
    constexpr int MI = 2 * BMT;
    constexpr int CA = BM / 8, CT = CA + BN / 8, NISS = CT / 4;
    __shared__ ushort Als[BM * BK];
    __shared__ ushort Bls[BN * BK];

    const int tid = threadIdx.x;
    const int w = tid >> 6, l = tid & 63;
    const int lr = l & 15, lg = l >> 4;
    const int wm = w >> 1, wn = w & 1;
    const int m0 = blockIdx.x * BM, n0 = blockIdx.y * BN;

    floatx4 acc[MI][4] = {};

    for (int k0 = 0; k0 < DMODEL; k0 += BK) {
        __syncthreads();
#pragma unroll
        for (int i = 0; i < NISS; i++) {
            const int c = w * NISS + i;
            const int cc = (c < CA) ? c : c - CA;
            const int row = (cc << 3) + (l >> 3);
            const int gcol = (((l & 7) ^ (row & 7)) << 3);
            if (c < CA)
                gld16(A + (size_t)(m0 + row) * DMODEL + k0 + gcol, &Als[cc << 9]);
            else
                gld16(W + (size_t)(n0 + row) * DMODEL + k0 + gcol, &Bls[cc << 9]);
        }
        __syncthreads();

#pragma unroll
        for (int kk = 0; kk < 2; kk++) {
            short8 af[MI], bfv[4];
            const int u = kk * 4 + lg;
#pragma unroll
            for (int i = 0; i < MI; i++) {
                const int r = wm * (BM / 2) + i * 16 + lr;
                af[i] = *(const short8*)&Als[r * 64 + ((u ^ (r & 7)) << 3)];
            }
#pragma unroll
            for (int j = 0; j < 4; j++) {
                const int r = wn * 64 + j * 16 + lr;
                bfv[j] = *(const short8*)&Bls[r * 64 + ((u ^ (r & 7)) << 3)];
            }
#pragma unroll
            for (int i = 0; i < MI; i++)
#pragma unroll
                for (int j = 0; j < 4; j++)
                    acc[i][j] = __builtin_amdgcn_mfma_f32_16x16x32_bf16(af[i], bfv[j], acc[i][j], 0, 0, 0);
        }
    }

#pragma unroll
    for (int i = 0; i < MI; i++) {
        const int rbase = m0 + wm * (BM / 2) + i * 16 + lg * 4;
#pragma unroll
        for (int j = 0; j < 4; j++) {
            const int cg = n0 + wn * 64 + j * 16 + lr;
            if constexpr (MODE == 1) {
                const float bb = bias0[cg];
#pragma unroll
                for (int p = 0; p < 4; p++)
                    Of[(size_t)(rbase + p) * DMODEL + cg] = acc[i][j][p] + bb;
            } else {
                const int sel = cg >> 10, cw = cg & 1023;
                const int h = cw >> 6, d = cw & 63;
                const float bb = (sel == 0 ? bias0 : sel == 1 ? bias1 : bias2)[cw];
                const int b = rbase >> 11, s = rbase & (SEQ - 1);
                if (sel == 2) {
                    uint2 pk;
                    pk.x = (uint)f2bf(acc[i][j][0] + bb) | ((uint)f2bf(acc[i][j][1] + bb) << 16);
                    pk.y = (uint)f2bf(acc[i][j][2] + bb) | ((uint)f2bf(acc[i][j][3] + bb) << 16);
                    *(uint2*)&Ov[((size_t)(b * NHEAD + h) * DKH + d) * SEQ + s] = pk;
                } else if (sel == 0) {
#pragma unroll
                    for (int p = 0; p < 4; p++)
                        Oq[((size_t)(b * NHEAD + h) * SEQ + s + p) * DKH + d] =
                            f2bf((acc[i][j][p] + bb) * SCL);   // fold softmax scale into Q
                } else {
#pragma unroll
                    for (int p = 0; p < 4; p++)
                        Ok[((size_t)(b * NHEAD + h) * SEQ + s + p) * DKH + d] = f2bf(acc[i][j][p] + bb);
                }
            }
        }
    }
}

// ---------------------------------------------------------------------------
// Flash attention, swapped QK^T in-lane softmax + T3-minimum double-buffer
// (issue next tile's global_load_lds BEFORE computing current; ONE barrier
// per tile) + T5 setprio around MFMA clusters.
// STAGE takes a TILE index t; offsets are t*KT rows (K) / t*KT cols (V^T).
// Grid (SEQ/128, B*H), 512 threads = 8 waves, wave owns 16 q-rows (q=lane&15).
// ---------------------------------------------------------------------------
__global__ __launch_bounds__(512) void attn_kernel(
    const ushort* __restrict__ Q, const ushort* __restrict__ K,
    const ushort* __restrict__ Vt, ushort* __restrict__ O) {
    constexpr int KT = 64, NT = SEQ / KT;
    __shared__ ushort Kls0[KT * 64], Kls1[KT * 64];   // [kpos][d], swizzled slots
    __shared__ ushort Vls0[KT * 64], Vls1[KT * 64];   // [d][kpos], swizzled slots
    __shared__ ushort Pls[8][16][68];                 // per-wave P [q][k]

    const int tid = threadIdx.x;
    const int w = tid >> 6, l = tid & 63;
    const int lr = l & 15, lg = l >> 4;
    const int lg4 = lg * 4;
    const int bh = blockIdx.y;
    const int q0 = blockIdx.x * 128;
    const ushort* Qh = Q  + (size_t)bh * SEQ * DKH;
    const ushort* Kh = K  + (size_t)bh * SEQ * DKH;
    const ushort* Vh = Vt + (size_t)bh * DKH * SEQ;

    // Q fragments (B-operand of swapped QK^T): col = q = lr
    short8 qf[2];
#pragma unroll
    for (int kk = 0; kk < 2; kk++)
        qf[kk] = *(const short8*)(Qh + (size_t)(q0 + w * 16 + lr) * DKH + kk * 32 + lg * 8);

    // staging: wave w stages rows w*8..w*8+7; per-lane global col pre-swizzled
    const int srow = w * 8 + (l >> 3);
    const int scol = ((l & 7) ^ ((l >> 3) & 7)) * 8;
    const ushort* Kg = Kh + (size_t)srow * DKH + scol;
    const ushort* Vg = Vh + (size_t)srow * SEQ + scol;

    floatx4 acc[4] = {};
    float mrun = -3e38f, lrun = 0.f;

// t = TILE index: K tile t starts at row t*KT; V^T tile t at column t*KT.
#define STAGE(t, kdst, vdst)                                          \
    do {                                                              \
        gld16(Kg + (size_t)(t) * (KT * DKH), (kdst) + w * 512);       \
        gld16(Vg + (size_t)(t) * KT, (vdst) + w * 512);               \
    } while (0)

#define COMPUTE(kb, vb)                                                         \
    do {                                                                        \
        floatx4 sa[4] = {};                                                     \
        __builtin_amdgcn_s_setprio(1);                                          \
        _Pragma("unroll")                                                       \
        for (int kk = 0; kk < 2; kk++) {                                        \
            const int u = kk * 4 + lg;                                          \
            _Pragma("unroll")                                                   \
            for (int n = 0; n < 4; n++) {                                       \
                const int r = n * 16 + lr;                                      \
                const short8 kf = *(const short8*)&(kb)[r * 64 + ((u ^ (r & 7)) << 3)]; \
                sa[n] = __builtin_amdgcn_mfma_f32_16x16x32_bf16(kf, qf[kk], sa[n], 0, 0, 0); \
            }                                                                   \
        }                                                                       \
        __builtin_amdgcn_s_setprio(0);                                          \
        float mx = fmaxf(fmaxf(fmaxf(sa[0][0], sa[0][1]), fmaxf(sa[0][2], sa[0][3])), \
                         fmaxf(fmaxf(sa[1][0], sa[1][1]), fmaxf(sa[1][2], sa[1][3]))); \
        mx = fmaxf(mx, fmaxf(fmaxf(fmaxf(sa[2][0], sa[2][1]), fmaxf(sa[2][2], sa[2][3])), \
                             fmaxf(fmaxf(sa[3][0], sa[3][1]), fmaxf(sa[3][2], sa[3][3])))); \
        mx = fmaxf(mx, __shfl_xor(mx, 16));                                     \
        mx = fmaxf(mx, __shfl_xor(mx, 32));                                     \
        const float mn = fmaxf(mrun, mx);                                       \
        const float corr = exp2f(mrun - mn);                                    \
        mrun = mn;                                                              \
        lrun *= corr;                                                           \
        _Pragma("unroll")                                                       \
        for (int p = 0; p < 4; p++) {                                           \
            const float cp = __shfl(corr, lg4 + p);                             \
            _Pragma("unroll")                                                   \
            for (int n = 0; n < 4; n++) acc[n][p] *= cp;                        \
        }                                                                       \
        float ps = 0.f;                                                         \
        _Pragma("unroll")                                                       \
        for (int n = 0; n < 4; n++)                                             \
            _Pragma("unroll")                                                   \
            for (int p = 0; p < 4; p++) {                                       \
                const float e = exp2f(sa[n][p] - mn);                           \
                sa[n][p] = e;                                                   \
                ps += e;                                                        \
            }                                                                   \
        ps += __shfl_xor(ps, 16);                                               \
        ps += __shfl_xor(ps, 32);                                               \
        lrun += ps;                                                             \
        _Pragma("unroll")                                                       \
        for (int n = 0; n < 4; n++) {                                           \
            uint2 pk;                                                           \
            pk.x = (uint)f2bf(sa[n][0]) | ((uint)f2bf(sa[n][1]) << 16);         \
            pk.y = (uint)f2bf(sa[n][2]) | ((uint)f2bf(sa[n][3]) << 16);         \
            *(uint2*)&Pls[w][lr][n * 16 + lg4] = pk;                            \
        }                                                                       \
        __builtin_amdgcn_s_setprio(1);                                          \
        _Pragma("unroll")                                                       \
        for (int kk = 0; kk < 2; kk++) {                                        \
            const int u = kk * 4 + lg;                                          \
            const short8 pf = *(const short8*)&Pls[w][lr][kk * 32 + lg * 8];    \
            _Pragma("unroll")                                                   \
            for (int n = 0; n < 4; n++) {                                       \
                const int r = n * 16 + lr;                                      \
                const short8 vf = *(const short8*)&(vb)[r * 64 + ((u ^ (r & 7)) << 3)]; \
                acc[n] = __builtin_amdgcn_mfma_f32_16x16x32_bf16(pf, vf, acc[n], 0, 0, 0); \
            }                                                                   \
        }                                                                       \
        __builtin_amdgcn_s_setprio(0);                                          \
    } while (0)

    // T3-minimum pipeline: prefetch next tile before computing current;
    // one barrier per tile (drains vmcnt -> prefetched tile ready).
    STAGE(0, Kls0, Vls0);
    __syncthreads();
#pragma unroll 1
    for (int it = 0; it < NT / 2 - 1; it++) {
        STAGE(2 * it + 1, Kls1, Vls1);
        COMPUTE(Kls0, Vls0);
        __syncthreads();
        STAGE(2 * it + 2, Kls0, Vls0);
        COMPUTE(Kls1, Vls1);
        __syncthreads();
    }
    STAGE(NT - 1, Kls1, Vls1);
    COMPUTE(Kls0, Vls0);
    __syncthreads();
    COMPUTE(Kls1, Vls1);
#undef STAGE
#undef COMPUTE

    // epilogue: O row = q = w*16 + lg4+p, col = h*64 + n*16+lr
    const int b = bh >> 4, h = bh & (NHEAD - 1);
#pragma unroll
    for (int p = 0; p < 4; p++) {
        const float lp = __shfl(lrun, lg4 + p);
        const float inv = 1.0f / lp;
        const int sr = q0 + w * 16 + lg4 + p;
#pragma unroll
        for (int n = 0; n < 4; n++) {
            const int d = n * 16 + lr;
            O[((size_t)(b * SEQ + sr)) * DMODEL + h * DKH + d] = f2bf(acc[n][p] * inv);
        }
    }
}

// ---------------------------------------------------------------------------
extern "C" void kernel_launch(void* const* d_in, const int* in_sizes, int n_in,
                              void* d_out, int out_size, void* d_ws, size_t ws_size,
                              hipStream_t stream) {
    const float* x  = (const float*)d_in[0];
    const float* Wq = (const float*)d_in[1];
    const float* bq = (const float*)d_in[2];
    const float* Wk = (const float*)d_in[3];
    const float* bk = (const float*)d_in[4];
    const float* Wv = (const float*)d_in[5];
    const float* bv = (const float*)d_in[6];
    const float* Wo = (const float*)d_in[7];
    const float* bo = (const float*)d_in[8];

    ushort* base = (ushort*)d_ws;
    ushort* xb  = base;                                  // 4M bf16
    ushort* wc  = xb  + (size_t)4 * 1024 * 1024;         // 3M  (Wq|Wk|Wv)
    ushort* wob = wc  + (size_t)3 * 1024 * 1024;         // 1M
    ushort* qws = wob + (size_t)1 * 1024 * 1024;         // 4M  Q [B,H,S,64] (pre-scaled)
    ushort* kws = qws + (size_t)4 * 1024 * 1024;         // 4M  K [B,H,S,64]
    ushort* vws = kws + (size_t)4 * 1024 * 1024;         // 4M  V^T [B,H,64,S]
    ushort* aws = vws + (size_t)4 * 1024 * 1024;         // 4M  attn out bf16

    hipLaunchKernelGGL(cvt_kernel, dim3(8192), dim3(256), 0, stream,
                       x, Wq, Wk, Wv, Wo, xb, wc, wob);

    hipLaunchKernelGGL((gemm_bf16<2, 0>), dim3(MTOT / 128, 3072 / 128), dim3(256), 0, stream,
                       xb, wc, bq, bk, bv, qws, kws, vws, (float*)nullptr);

    hipLaunchKernelGGL(attn_kernel, dim3(SEQ / 128, BATCH * NHEAD), dim3(512), 0, stream,
                       qws, kws, vws, aws);

    hipLaunchKernelGGL((gemm_bf16<1, 1>), dim3(MTOT / 64, DMODEL / 128), dim3(256), 0, stream,
                       aws, wob, bo, (const float*)nullptr, (const float*)nullptr,
                       (ushort*)nullptr, (ushort*)nullptr, (ushort*)nullptr, (float*)d_out);
}

// Round 8
// 140.175 us; speedup vs baseline: 3.4141x; 1.0671x over previous
//
#include <hip/hip_runtime.h>

constexpr int DMODEL = 1024;
constexpr int NHEAD  = 16;
constexpr int DKH    = 64;
constexpr int BATCH  = 2;
constexpr int SEQ    = 2048;
constexpr int MTOT   = BATCH * SEQ;   // 4096
constexpr float SCL  = 0.18033688011112042f;   // (1/sqrt(64)) * log2(e)

typedef __attribute__((ext_vector_type(8))) short short8;
typedef __attribute__((ext_vector_type(4))) float floatx4;

// fp32 -> bf16 round-to-nearest-even
__device__ __forceinline__ ushort f2bf(float f) {
    unsigned u = __builtin_bit_cast(unsigned, f);
    u = (u + 0x7fffu + ((u >> 16) & 1u)) >> 16;
    return (ushort)u;
}

// async 16B global->LDS (HW writes lds_base + lane*16)
__device__ __forceinline__ void gld16(const ushort* g, ushort* l) {
    __builtin_amdgcn_global_load_lds(
        (const __attribute__((address_space(1))) void*)g,
        (__attribute__((address_space(3))) void*)l, 16, 0, 0);
}

// ---------------------------------------------------------------------------
// Convert pass: x -> xb bf16; Wq/Wk/Wv -> wc bf16 [3072,1024]; Wo -> wob bf16.
// ---------------------------------------------------------------------------
__global__ __launch_bounds__(256) void cvt_kernel(
    const float* __restrict__ x,  const float* __restrict__ wq,
    const float* __restrict__ wk, const float* __restrict__ wv,
    const float* __restrict__ wo,
    ushort* __restrict__ xb, ushort* __restrict__ wc, ushort* __restrict__ wob) {
    const int id = blockIdx.x * 256 + threadIdx.x;        // 0 .. 2M-1
    const float* src;
    ushort* dst;
    if (id < (1 << 20)) {
        src = x + (size_t)id * 4;
        dst = xb + (size_t)id * 4;
    } else {
        const int t = id - (1 << 20);
        const int seg = t >> 18;                           // 0..3
        const size_t off = (size_t)(t & 0x3ffff) * 4;
        src = (seg == 0 ? wq : seg == 1 ? wk : seg == 2 ? wv : wo) + off;
        dst = (seg < 3) ? (wc + ((size_t)seg << 20) + off) : (wob + off);
    }
    const float4 v = *(const float4*)src;
    uint2 o;
    o.x = (uint)f2bf(v.x) | ((uint)f2bf(v.y) << 16);
    o.y = (uint)f2bf(v.z) | ((uint)f2bf(v.w) << 16);
    *(uint2*)dst = o;
}

// ---------------------------------------------------------------------------
// bf16 GEMM  Y = A @ W^T + bias (NT).  BK=64, global_load_lds(16B), XOR
// swizzle via pre-swizzled global source.  MODE 0: fused QKV epilogue
// (Q scaled by SCL; V transposed).  MODE 1: fp32 output.
// ---------------------------------------------------------------------------
template <int BMT, int MODE>
__global__ __launch_bounds__(256) void gemm_bf16(
    const ushort* __restrict__ A, const ushort* __restrict__ W,
    const float* __restrict__ bias0, const float* __restrict__ bias1,
    const float* __restrict__ bias2,
    ushort* __restrict__ Oq, ushort* __restrict__ Ok, ushort* __restrict__ Ov,
    float* __restrict__ Of) {
    constexpr int BM = 64 * BMT, BN = 128, BK = 64;
    constexpr int MI = 2 * BMT;
    constexpr int CA = BM / 8, CT = CA + BN / 8, NISS = CT / 4;
    __shared__ ushort Als[BM * BK];
    __shared__ ushort Bls[BN * BK];

    const int tid = threadIdx.x;
    const int w = tid >> 6, l = tid & 63;
    const int lr = l & 15, lg = l >> 4;
    const int wm = w >> 1, wn = w & 1;
    const int m0 = blockIdx.x * BM, n0 = blockIdx.y * BN;

    floatx4 acc[MI][4] = {};

    for (int k0 = 0; k0 < DMODEL; k0 += BK) {
        __syncthreads();
#pragma unroll
        for (int i = 0; i < NISS; i++) {
            const int c = w * NISS + i;
            const int cc = (c < CA) ? c : c - CA;
            const int row = (cc << 3) + (l >> 3);
            const int gcol = (((l & 7) ^ (row & 7)) << 3);
            if (c < CA)
                gld16(A + (size_t)(m0 + row) * DMODEL + k0 + gcol, &Als[cc << 9]);
            else
                gld16(W + (size_t)(n0 + row) * DMODEL + k0 + gcol, &Bls[cc << 9]);
        }
        __syncthreads();

#pragma unroll
        for (int kk = 0; kk < 2; kk++) {
            short8 af[MI], bfv[4];
            const int u = kk * 4 + lg;
#pragma unroll
            for (int i = 0; i < MI; i++) {
                const int r = wm * (BM / 2) + i * 16 + lr;
                af[i] = *(const short8*)&Als[r * 64 + ((u ^ (r & 7)) << 3)];
            }
#pragma unroll
            for (int j = 0; j < 4; j++) {
                const int r = wn * 64 + j * 16 + lr;
                bfv[j] = *(const short8*)&Bls[r * 64 + ((u ^ (r & 7)) << 3)];
            }
#pragma unroll
            for (int i = 0; i < MI; i++)
#pragma unroll
                for (int j = 0; j < 4; j++)
                    acc[i][j] = __builtin_amdgcn_mfma_f32_16x16x32_bf16(af[i], bfv[j], acc[i][j], 0, 0, 0);
        }
    }

#pragma unroll
    for (int i = 0; i < MI; i++) {
        const int rbase = m0 + wm * (BM / 2) + i * 16 + lg * 4;
#pragma unroll
        for (int j = 0; j < 4; j++) {
            const int cg = n0 + wn * 64 + j * 16 + lr;
            if constexpr (MODE == 1) {
                const float bb = bias0[cg];
#pragma unroll
                for (int p = 0; p < 4; p++)
                    Of[(size_t)(rbase + p) * DMODEL + cg] = acc[i][j][p] + bb;
            } else {
                const int sel = cg >> 10, cw = cg & 1023;
                const int h = cw >> 6, d = cw & 63;
                const float bb = (sel == 0 ? bias0 : sel == 1 ? bias1 : bias2)[cw];
                const int b = rbase >> 11, s = rbase & (SEQ - 1);
                if (sel == 2) {
                    uint2 pk;
                    pk.x = (uint)f2bf(acc[i][j][0] + bb) | ((uint)f2bf(acc[i][j][1] + bb) << 16);
                    pk.y = (uint)f2bf(acc[i][j][2] + bb) | ((uint)f2bf(acc[i][j][3] + bb) << 16);
                    *(uint2*)&Ov[((size_t)(b * NHEAD + h) * DKH + d) * SEQ + s] = pk;
                } else if (sel == 0) {
#pragma unroll
                    for (int p = 0; p < 4; p++)
                        Oq[((size_t)(b * NHEAD + h) * SEQ + s + p) * DKH + d] =
                            f2bf((acc[i][j][p] + bb) * SCL);   // fold softmax scale into Q
                } else {
#pragma unroll
                    for (int p = 0; p < 4; p++)
                        Ok[((size_t)(b * NHEAD + h) * SEQ + s + p) * DKH + d] = f2bf(acc[i][j][p] + bb);
                }
            }
        }
    }
}

// ---------------------------------------------------------------------------
// Flash attention, swapped QK^T in-lane softmax + T3-minimum double-buffer
// + T5 setprio + T12 cvt_pk P-conversion + T13 defer-max (THR=10, log2 dom).
// STAGE takes a TILE index t; offsets are t*KT rows (K) / t*KT cols (V^T).
// Grid (SEQ/128, B*H), 512 threads = 8 waves, wave owns 16 q-rows (q=lane&15).
// ---------------------------------------------------------------------------
__global__ __launch_bounds__(512) void attn_kernel(
    const ushort* __restrict__ Q, const ushort* __restrict__ K,
    const ushort* __restrict__ Vt, ushort* __restrict__ O) {
    constexpr int KT = 64, NT = SEQ / KT;
    __shared__ ushort Kls0[KT * 64], Kls1[KT * 64];   // [kpos][d], swizzled slots
    __shared__ ushort Vls0[KT * 64], Vls1[KT * 64];   // [d][kpos], swizzled slots
    __shared__ ushort Pls[8][16][68];                 // per-wave P [q][k]

    const int tid = threadIdx.x;
    const int w = tid >> 6, l = tid & 63;
    const int lr = l & 15, lg = l >> 4;
    const int lg4 = lg * 4;
    const int bh = blockIdx.y;
    const int q0 = blockIdx.x * 128;
    const ushort* Qh = Q  + (size_t)bh * SEQ * DKH;
    const ushort* Kh = K  + (size_t)bh * SEQ * DKH;
    const ushort* Vh = Vt + (size_t)bh * DKH * SEQ;

    // Q fragments (B-operand of swapped QK^T): col = q = lr
    short8 qf[2];
#pragma unroll
    for (int kk = 0; kk < 2; kk++)
        qf[kk] = *(const short8*)(Qh + (size_t)(q0 + w * 16 + lr) * DKH + kk * 32 + lg * 8);

    // staging: wave w stages rows w*8..w*8+7; per-lane global col pre-swizzled
    const int srow = w * 8 + (l >> 3);
    const int scol = ((l & 7) ^ ((l >> 3) & 7)) * 8;
    const ushort* Kg = Kh + (size_t)srow * DKH + scol;
    const ushort* Vg = Vh + (size_t)srow * SEQ + scol;

    floatx4 acc[4] = {};
    float mrun = -3e38f, lrun = 0.f;

// t = TILE index: K tile t starts at row t*KT; V^T tile t at column t*KT.
#define STAGE(t, kdst, vdst)                                          \
    do {                                                              \
        gld16(Kg + (size_t)(t) * (KT * DKH), (kdst) + w * 512);       \
        gld16(Vg + (size_t)(t) * KT, (vdst) + w * 512);               \
    } while (0)

#define COMPUTE(kb, vb)                                                         \
    do {                                                                        \
        floatx4 sa[4] = {};                                                     \
        __builtin_amdgcn_s_setprio(1);                                          \
        _Pragma("unroll")                                                       \
        for (int kk = 0; kk < 2; kk++) {                                        \
            const int u = kk * 4 + lg;                                          \
            _Pragma("unroll")                                                   \
            for (int n = 0; n < 4; n++) {                                       \
                const int r = n * 16 + lr;                                      \
                const short8 kf = *(const short8*)&(kb)[r * 64 + ((u ^ (r & 7)) << 3)]; \
                sa[n] = __builtin_amdgcn_mfma_f32_16x16x32_bf16(kf, qf[kk], sa[n], 0, 0, 0); \
            }                                                                   \
        }                                                                       \
        __builtin_amdgcn_s_setprio(0);                                          \
        float mx = fmaxf(fmaxf(fmaxf(sa[0][0], sa[0][1]), fmaxf(sa[0][2], sa[0][3])), \
                         fmaxf(fmaxf(sa[1][0], sa[1][1]), fmaxf(sa[1][2], sa[1][3]))); \
        mx = fmaxf(mx, fmaxf(fmaxf(fmaxf(sa[2][0], sa[2][1]), fmaxf(sa[2][2], sa[2][3])), \
                             fmaxf(fmaxf(sa[3][0], sa[3][1]), fmaxf(sa[3][2], sa[3][3])))); \
        mx = fmaxf(mx, __shfl_xor(mx, 16));                                     \
        mx = fmaxf(mx, __shfl_xor(mx, 32));                                     \
        if (__any(mx - mrun > 10.0f)) {   /* T13 defer-max */                   \
            const float mn = fmaxf(mrun, mx);                                   \
            const float corr = exp2f(mrun - mn);                                \
            mrun = mn;                                                          \
            lrun *= corr;                                                       \
            _Pragma("unroll")                                                   \
            for (int p = 0; p < 4; p++) {                                       \
                const float cp = __shfl(corr, lg4 + p);                         \
                _Pragma("unroll")                                               \
                for (int n = 0; n < 4; n++) acc[n][p] *= cp;                    \
            }                                                                   \
        }                                                                       \
        float ps = 0.f;                                                         \
        _Pragma("unroll")                                                       \
        for (int n = 0; n < 4; n++)                                             \
            _Pragma("unroll")                                                   \
            for (int p = 0; p < 4; p++) {                                       \
                const float e = exp2f(sa[n][p] - mrun);                         \
                sa[n][p] = e;                                                   \
                ps += e;                                                        \
            }                                                                   \
        ps += __shfl_xor(ps, 16);                                               \
        ps += __shfl_xor(ps, 32);                                               \
        lrun += ps;                                                             \
        _Pragma("unroll")                                                       \
        for (int n = 0; n < 4; n++) {   /* T12 cvt_pk: lo=S0, hi=S1 */          \
            uint2 pk;                                                           \
            asm("v_cvt_pk_bf16_f32 %0, %1, %2" : "=v"(pk.x) : "v"(sa[n][0]), "v"(sa[n][1])); \
            asm("v_cvt_pk_bf16_f32 %0, %1, %2" : "=v"(pk.y) : "v"(sa[n][2]), "v"(sa[n][3])); \
            *(uint2*)&Pls[w][lr][n * 16 + lg4] = pk;                            \
        }                                                                       \
        __builtin_amdgcn_s_setprio(1);                                          \
        _Pragma("unroll")                                                       \
        for (int kk = 0; kk < 2; kk++) {                                        \
            const int u = kk * 4 + lg;                                          \
            const short8 pf = *(const short8*)&Pls[w][lr][kk * 32 + lg * 8];    \
            _Pragma("unroll")                                                   \
            for (int n = 0; n < 4; n++) {                                       \
                const int r = n * 16 + lr;                                      \
                const short8 vf = *(const short8*)&(vb)[r * 64 + ((u ^ (r & 7)) << 3)]; \
                acc[n] = __builtin_amdgcn_mfma_f32_16x16x32_bf16(pf, vf, acc[n], 0, 0, 0); \
            }                                                                   \
        }                                                                       \
        __builtin_amdgcn_s_setprio(0);                                          \
    } while (0)

    // T3-minimum pipeline: prefetch next tile before computing current;
    // one barrier per tile (drains vmcnt -> prefetched tile ready).
    STAGE(0, Kls0, Vls0);
    __syncthreads();
#pragma unroll 1
    for (int it = 0; it < NT / 2 - 1; it++) {
        STAGE(2 * it + 1, Kls1, Vls1);
        COMPUTE(Kls0, Vls0);
        __syncthreads();
        STAGE(2 * it + 2, Kls0, Vls0);
        COMPUTE(Kls1, Vls1);
        __syncthreads();
    }
    STAGE(NT - 1, Kls1, Vls1);
    COMPUTE(Kls0, Vls0);
    __syncthreads();
    COMPUTE(Kls1, Vls1);
#undef STAGE
#undef COMPUTE

    // epilogue: O row = q = w*16 + lg4+p, col = h*64 + n*16+lr
    const int b = bh >> 4, h = bh & (NHEAD - 1);
#pragma unroll
    for (int p = 0; p < 4; p++) {
        const float lp = __shfl(lrun, lg4 + p);
        const float inv = 1.0f / lp;
        const int sr = q0 + w * 16 + lg4 + p;
#pragma unroll
        for (int n = 0; n < 4; n++) {
            const int d = n * 16 + lr;
            O[((size_t)(b * SEQ + sr)) * DMODEL + h * DKH + d] = f2bf(acc[n][p] * inv);
        }
    }
}

// ---------------------------------------------------------------------------
extern "C" void kernel_launch(void* const* d_in, const int* in_sizes, int n_in,
                              void* d_out, int out_size, void* d_ws, size_t ws_size,
                              hipStream_t stream) {
    const float* x  = (const float*)d_in[0];
    const float* Wq = (const float*)d_in[1];
    const float* bq = (const float*)d_in[2];
    const float* Wk = (const float*)d_in[3];
    const float* bk = (const float*)d_in[4];
    const float* Wv = (const float*)d_in[5];
    const float* bv = (const float*)d_in[6];
    const float* Wo = (const float*)d_in[7];
    const float* bo = (const float*)d_in[8];

    ushort* base = (ushort*)d_ws;
    ushort* xb  = base;                                  // 4M bf16
    ushort* wc  = xb  + (size_t)4 * 1024 * 1024;         // 3M  (Wq|Wk|Wv)
    ushort* wob = wc  + (size_t)3 * 1024 * 1024;         // 1M
    ushort* qws = wob + (size_t)1 * 1024 * 1024;         // 4M  Q [B,H,S,64] (pre-scaled)
    ushort* kws = qws + (size_t)4 * 1024 * 1024;         // 4M  K [B,H,S,64]
    ushort* vws = kws + (size_t)4 * 1024 * 1024;         // 4M  V^T [B,H,64,S]
    ushort* aws = vws + (size_t)4 * 1024 * 1024;         // 4M  attn out bf16

    hipLaunchKernelGGL(cvt_kernel, dim3(8192), dim3(256), 0, stream,
                       x, Wq, Wk, Wv, Wo, xb, wc, wob);

    hipLaunchKernelGGL((gemm_bf16<2, 0>), dim3(MTOT / 128, 3072 / 128), dim3(256), 0, stream,
                       xb, wc, bq, bk, bv, qws, kws, vws, (float*)nullptr);

    hipLaunchKernelGGL(attn_kernel, dim3(SEQ / 128, BATCH * NHEAD), dim3(512), 0, stream,
                       qws, kws, vws, aws);

    hipLaunchKernelGGL((gemm_bf16<1, 1>), dim3(MTOT / 64, DMODEL / 128), dim3(256), 0, stream,
                       aws, wob, bo, (const float*)nullptr, (const float*)nullptr,
                       (ushort*)nullptr, (ushort*)nullptr, (ushort*)nullptr, (float*)d_out);
}

// Round 9
// 136.052 us; speedup vs baseline: 3.5175x; 1.0303x over previous
//
#include <hip/hip_runtime.h>

constexpr int DMODEL = 1024;
constexpr int NHEAD  = 16;
constexpr int DKH    = 64;
constexpr int BATCH  = 2;
constexpr int SEQ    = 2048;
constexpr int MTOT   = BATCH * SEQ;   // 4096
constexpr float SCL  = 0.18033688011112042f;   // (1/sqrt(64)) * log2(e)

typedef __attribute__((ext_vector_type(8))) short short8;
typedef __attribute__((ext_vector_type(4))) float floatx4;

// fp32 -> bf16 round-to-nearest-even
__device__ __forceinline__ ushort f2bf(float f) {
    unsigned u = __builtin_bit_cast(unsigned, f);
    u = (u + 0x7fffu + ((u >> 16) & 1u)) >> 16;
    return (ushort)u;
}

// async 16B global->LDS (HW writes lds_base + lane*16)
__device__ __forceinline__ void gld16(const ushort* g, ushort* l) {
    __builtin_amdgcn_global_load_lds(
        (const __attribute__((address_space(1))) void*)g,
        (__attribute__((address_space(3))) void*)l, 16, 0, 0);
}

// ---------------------------------------------------------------------------
// Convert pass: x -> xb bf16; Wq/Wk/Wv -> wc bf16 [3072,1024]; Wo -> wob bf16.
// ---------------------------------------------------------------------------
__global__ __launch_bounds__(256) void cvt_kernel(
    const float* __restrict__ x,  const float* __restrict__ wq,
    const float* __restrict__ wk, const float* __restrict__ wv,
    const float* __restrict__ wo,
    ushort* __restrict__ xb, ushort* __restrict__ wc, ushort* __restrict__ wob) {
    const int id = blockIdx.x * 256 + threadIdx.x;        // 0 .. 2M-1
    const float* src;
    ushort* dst;
    if (id < (1 << 20)) {
        src = x + (size_t)id * 4;
        dst = xb + (size_t)id * 4;
    } else {
        const int t = id - (1 << 20);
        const int seg = t >> 18;                           // 0..3
        const size_t off = (size_t)(t & 0x3ffff) * 4;
        src = (seg == 0 ? wq : seg == 1 ? wk : seg == 2 ? wv : wo) + off;
        dst = (seg < 3) ? (wc + ((size_t)seg << 20) + off) : (wob + off);
    }
    const float4 v = *(const float4*)src;
    uint2 o;
    o.x = (uint)f2bf(v.x) | ((uint)f2bf(v.y) << 16);
    o.y = (uint)f2bf(v.z) | ((uint)f2bf(v.w) << 16);
    *(uint2*)dst = o;
}

// ---------------------------------------------------------------------------
// bf16 GEMM  Y = A @ W^T + bias (NT).  BK=64, global_load_lds(16B), XOR
// swizzle via pre-swizzled global source.
// MODE 0: fused QKV epilogue -> Q^T [B,H,64,S] (scaled by SCL, packed),
//         K [B,H,S,64] (scalar), V^T [B,H,64,S] (packed).
// MODE 1: fp32 [M,1024] output (final projection).
// ---------------------------------------------------------------------------
template <int BMT, int MODE>
__global__ __launch_bounds__(256) void gemm_bf16(
    const ushort* __restrict__ A, const ushort* __restrict__ W,
    const float* __restrict__ bias0, const float* __restrict__ bias1,
    const float* __restrict__ bias2,
    ushort* __restrict__ Oq, ushort* __restrict__ Ok, ushort* __restrict__ Ov,
    float* __restrict__ Of) {
    constexpr int BM = 64 * BMT, BN = 128, BK = 64;
    constexpr int MI = 2 * BMT;
    constexpr int CA = BM / 8, CT = CA + BN / 8, NISS = CT / 4;
    __shared__ ushort Als[BM * BK];
    __shared__ ushort Bls[BN * BK];

    const int tid = threadIdx.x;
    const int w = tid >> 6, l = tid & 63;
    const int lr = l & 15, lg = l >> 4;
    const int wm = w >> 1, wn = w & 1;
    const int m0 = blockIdx.x * BM, n0 = blockIdx.y * BN;

    floatx4 acc[MI][4] = {};

    for (int k0 = 0; k0 < DMODEL; k0 += BK) {
        __syncthreads();
#pragma unroll
        for (int i = 0; i < NISS; i++) {
            const int c = w * NISS + i;
            const int cc = (c < CA) ? c : c - CA;
            const int row = (cc << 3) + (l >> 3);
            const int gcol = (((l & 7) ^ (row & 7)) << 3);
            if (c < CA)
                gld16(A + (size_t)(m0 + row) * DMODEL + k0 + gcol, &Als[cc << 9]);
            else
                gld16(W + (size_t)(n0 + row) * DMODEL + k0 + gcol, &Bls[cc << 9]);
        }
        __syncthreads();

#pragma unroll
        for (int kk = 0; kk < 2; kk++) {
            short8 af[MI], bfv[4];
            const int u = kk * 4 + lg;
#pragma unroll
            for (int i = 0; i < MI; i++) {
                const int r = wm * (BM / 2) + i * 16 + lr;
                af[i] = *(const short8*)&Als[r * 64 + ((u ^ (r & 7)) << 3)];
            }
#pragma unroll
            for (int j = 0; j < 4; j++) {
                const int r = wn * 64 + j * 16 + lr;
                bfv[j] = *(const short8*)&Bls[r * 64 + ((u ^ (r & 7)) << 3)];
            }
#pragma unroll
            for (int i = 0; i < MI; i++)
#pragma unroll
                for (int j = 0; j < 4; j++)
                    acc[i][j] = __builtin_amdgcn_mfma_f32_16x16x32_bf16(af[i], bfv[j], acc[i][j], 0, 0, 0);
        }
    }

#pragma unroll
    for (int i = 0; i < MI; i++) {
        const int rbase = m0 + wm * (BM / 2) + i * 16 + lg * 4;
#pragma unroll
        for (int j = 0; j < 4; j++) {
            const int cg = n0 + wn * 64 + j * 16 + lr;
            if constexpr (MODE == 1) {
                const float bb = bias0[cg];
#pragma unroll
                for (int p = 0; p < 4; p++)
                    Of[(size_t)(rbase + p) * DMODEL + cg] = acc[i][j][p] + bb;
            } else {
                const int sel = cg >> 10, cw = cg & 1023;
                const int h = cw >> 6, d = cw & 63;
                const float bb = (sel == 0 ? bias0 : sel == 1 ? bias1 : bias2)[cw];
                const int b = rbase >> 11, s = rbase & (SEQ - 1);
                if (sel == 2) {
                    uint2 pk;
                    pk.x = (uint)f2bf(acc[i][j][0] + bb) | ((uint)f2bf(acc[i][j][1] + bb) << 16);
                    pk.y = (uint)f2bf(acc[i][j][2] + bb) | ((uint)f2bf(acc[i][j][3] + bb) << 16);
                    *(uint2*)&Ov[((size_t)(b * NHEAD + h) * DKH + d) * SEQ + s] = pk;
                } else if (sel == 0) {
                    // Q transposed [B,H,64,S], pre-scaled: packed like V
                    uint2 pk;
                    pk.x = (uint)f2bf((acc[i][j][0] + bb) * SCL) |
                           ((uint)f2bf((acc[i][j][1] + bb) * SCL) << 16);
                    pk.y = (uint)f2bf((acc[i][j][2] + bb) * SCL) |
                           ((uint)f2bf((acc[i][j][3] + bb) * SCL) << 16);
                    *(uint2*)&Oq[((size_t)(b * NHEAD + h) * DKH + d) * SEQ + s] = pk;
                } else {
#pragma unroll
                    for (int p = 0; p < 4; p++)
                        Ok[((size_t)(b * NHEAD + h) * SEQ + s + p) * DKH + d] = f2bf(acc[i][j][p] + bb);
                }
            }
        }
    }
}

// ---------------------------------------------------------------------------
// Flash attention, swapped QK^T in-lane softmax + T3-minimum double-buffer
// + T5 setprio + T12 cvt_pk + T13 defer-max + l-sum via ones-column MFMA
// (accl = P @ 1 accumulates row-sums with the SAME C-layout as acc -> no
// epilogue shuffles, no per-tile ps adds).
// Q input is TRANSPOSED [B,H,64,S] (pre-scaled by SCL).
// Grid (SEQ/128, B*H), 512 threads = 8 waves, wave owns 16 q-rows (q=lane&15).
// ---------------------------------------------------------------------------
__global__ __launch_bounds__(512) void attn_kernel(
    const ushort* __restrict__ Qt, const ushort* __restrict__ K,
    const ushort* __restrict__ Vt, ushort* __restrict__ O) {
    constexpr int KT = 64, NT = SEQ / KT;
    __shared__ ushort Kls0[KT * 64], Kls1[KT * 64];   // [kpos][d], swizzled slots
    __shared__ ushort Vls0[KT * 64], Vls1[KT * 64];   // [d][kpos], swizzled slots
    __shared__ ushort Pls[8][16][68];                 // per-wave P [q][k]

    const int tid = threadIdx.x;
    const int w = tid >> 6, l = tid & 63;
    const int lr = l & 15, lg = l >> 4;
    const int lg4 = lg * 4;
    const int bh = blockIdx.y;
    const int q0 = blockIdx.x * 128;
    const ushort* Qh = Qt + (size_t)bh * DKH * SEQ;
    const ushort* Kh = K  + (size_t)bh * SEQ * DKH;
    const ushort* Vh = Vt + (size_t)bh * DKH * SEQ;

    // Q fragments (B-operand of swapped QK^T) from transposed Q: col = q = lr
    short8 qf[2];
#pragma unroll
    for (int kk = 0; kk < 2; kk++)
#pragma unroll
        for (int j = 0; j < 8; j++)
            ((ushort*)&qf[kk])[j] =
                Qh[(size_t)(kk * 32 + lg * 8 + j) * SEQ + q0 + w * 16 + lr];

    // bf16 ones vector for the l-sum MFMA column
    short8 ones;
#pragma unroll
    for (int j = 0; j < 8; j++) ones[j] = (short)0x3F80;

    // staging: wave w stages rows w*8..w*8+7; per-lane global col pre-swizzled
    const int srow = w * 8 + (l >> 3);
    const int scol = ((l & 7) ^ ((l >> 3) & 7)) * 8;
    const ushort* Kg = Kh + (size_t)srow * DKH + scol;
    const ushort* Vg = Vh + (size_t)srow * SEQ + scol;

    floatx4 acc[4] = {};
    floatx4 accl = {};
    float mrun = -3e38f;

// t = TILE index: K tile t starts at row t*KT; V^T tile t at column t*KT.
#define STAGE(t, kdst, vdst)                                          \
    do {                                                              \
        gld16(Kg + (size_t)(t) * (KT * DKH), (kdst) + w * 512);       \
        gld16(Vg + (size_t)(t) * KT, (vdst) + w * 512);               \
    } while (0)

#define COMPUTE(kb, vb)                                                         \
    do {                                                                        \
        floatx4 sa[4] = {};                                                     \
        __builtin_amdgcn_s_setprio(1);                                          \
        _Pragma("unroll")                                                       \
        for (int kk = 0; kk < 2; kk++) {                                        \
            const int u = kk * 4 + lg;                                          \
            _Pragma("unroll")                                                   \
            for (int n = 0; n < 4; n++) {                                       \
                const int r = n * 16 + lr;                                      \
                const short8 kf = *(const short8*)&(kb)[r * 64 + ((u ^ (r & 7)) << 3)]; \
                sa[n] = __builtin_amdgcn_mfma_f32_16x16x32_bf16(kf, qf[kk], sa[n], 0, 0, 0); \
            }                                                                   \
        }                                                                       \
        __builtin_amdgcn_s_setprio(0);                                          \
        float mx = fmaxf(fmaxf(fmaxf(sa[0][0], sa[0][1]), fmaxf(sa[0][2], sa[0][3])), \
                         fmaxf(fmaxf(sa[1][0], sa[1][1]), fmaxf(sa[1][2], sa[1][3]))); \
        mx = fmaxf(mx, fmaxf(fmaxf(fmaxf(sa[2][0], sa[2][1]), fmaxf(sa[2][2], sa[2][3])), \
                             fmaxf(fmaxf(sa[3][0], sa[3][1]), fmaxf(sa[3][2], sa[3][3])))); \
        mx = fmaxf(mx, __shfl_xor(mx, 16));                                     \
        mx = fmaxf(mx, __shfl_xor(mx, 32));                                     \
        if (__any(mx - mrun > 10.0f)) {   /* T13 defer-max */                   \
            const float mn = fmaxf(mrun, mx);                                   \
            const float corr = exp2f(mrun - mn);                                \
            mrun = mn;                                                          \
            _Pragma("unroll")                                                   \
            for (int p = 0; p < 4; p++) {                                       \
                const float cp = __shfl(corr, lg4 + p);                         \
                _Pragma("unroll")                                               \
                for (int n = 0; n < 4; n++) acc[n][p] *= cp;                    \
                accl[p] *= cp;                                                  \
            }                                                                   \
        }                                                                       \
        _Pragma("unroll")                                                       \
        for (int n = 0; n < 4; n++)                                             \
            _Pragma("unroll")                                                   \
            for (int p = 0; p < 4; p++)                                         \
                sa[n][p] = exp2f(sa[n][p] - mrun);                              \
        _Pragma("unroll")                                                       \
        for (int n = 0; n < 4; n++) {   /* T12 cvt_pk */                        \
            uint2 pk;                                                           \
            asm("v_cvt_pk_bf16_f32 %0, %1, %2" : "=v"(pk.x) : "v"(sa[n][0]), "v"(sa[n][1])); \
            asm("v_cvt_pk_bf16_f32 %0, %1, %2" : "=v"(pk.y) : "v"(sa[n][2]), "v"(sa[n][3])); \
            *(uint2*)&Pls[w][lr][n * 16 + lg4] = pk;                            \
        }                                                                       \
        __builtin_amdgcn_s_setprio(1);                                          \
        _Pragma("unroll")                                                       \
        for (int kk = 0; kk < 2; kk++) {                                        \
            const int u = kk * 4 + lg;                                          \
            const short8 pf = *(const short8*)&Pls[w][lr][kk * 32 + lg * 8];    \
            _Pragma("unroll")                                                   \
            for (int n = 0; n < 4; n++) {                                       \
                const int r = n * 16 + lr;                                      \
                const short8 vf = *(const short8*)&(vb)[r * 64 + ((u ^ (r & 7)) << 3)]; \
                acc[n] = __builtin_amdgcn_mfma_f32_16x16x32_bf16(pf, vf, acc[n], 0, 0, 0); \
            }                                                                   \
            accl = __builtin_amdgcn_mfma_f32_16x16x32_bf16(pf, ones, accl, 0, 0, 0); \
        }                                                                       \
        __builtin_amdgcn_s_setprio(0);                                          \
    } while (0)

    // T3-minimum pipeline: prefetch next tile before computing current;
    // one barrier per tile (drains vmcnt -> prefetched tile ready).
    STAGE(0, Kls0, Vls0);
    __syncthreads();
#pragma unroll 1
    for (int it = 0; it < NT / 2 - 1; it++) {
        STAGE(2 * it + 1, Kls1, Vls1);
        COMPUTE(Kls0, Vls0);
        __syncthreads();
        STAGE(2 * it + 2, Kls0, Vls0);
        COMPUTE(Kls1, Vls1);
        __syncthreads();
    }
    STAGE(NT - 1, Kls1, Vls1);
    COMPUTE(Kls0, Vls0);
    __syncthreads();
    COMPUTE(Kls1, Vls1);
#undef STAGE
#undef COMPUTE

    // epilogue: O row = q = w*16 + lg4+p (same indexing as accl), col = h*64+n*16+lr
    const int b = bh >> 4, h = bh & (NHEAD - 1);
#pragma unroll
    for (int p = 0; p < 4; p++) {
        const float inv = 1.0f / accl[p];
        const int sr = q0 + w * 16 + lg4 + p;
#pragma unroll
        for (int n = 0; n < 4; n++) {
            const int d = n * 16 + lr;
            O[((size_t)(b * SEQ + sr)) * DMODEL + h * DKH + d] = f2bf(acc[n][p] * inv);
        }
    }
}

// ---------------------------------------------------------------------------
extern "C" void kernel_launch(void* const* d_in, const int* in_sizes, int n_in,
                              void* d_out, int out_size, void* d_ws, size_t ws_size,
                              hipStream_t stream) {
    const float* x  = (const float*)d_in[0];
    const float* Wq = (const float*)d_in[1];
    const float* bq = (const float*)d_in[2];
    const float* Wk = (const float*)d_in[3];
    const float* bk = (const float*)d_in[4];
    const float* Wv = (const float*)d_in[5];
    const float* bv = (const float*)d_in[6];
    const float* Wo = (const float*)d_in[7];
    const float* bo = (const float*)d_in[8];

    ushort* base = (ushort*)d_ws;
    ushort* xb  = base;                                  // 4M bf16
    ushort* wc  = xb  + (size_t)4 * 1024 * 1024;         // 3M  (Wq|Wk|Wv)
    ushort* wob = wc  + (size_t)3 * 1024 * 1024;         // 1M
    ushort* qws = wob + (size_t)1 * 1024 * 1024;         // 4M  Q^T [B,H,64,S] (pre-scaled)
    ushort* kws = qws + (size_t)4 * 1024 * 1024;         // 4M  K [B,H,S,64]
    ushort* vws = kws + (size_t)4 * 1024 * 1024;         // 4M  V^T [B,H,64,S]
    ushort* aws = vws + (size_t)4 * 1024 * 1024;         // 4M  attn out bf16

    hipLaunchKernelGGL(cvt_kernel, dim3(8192), dim3(256), 0, stream,
                       x, Wq, Wk, Wv, Wo, xb, wc, wob);

    hipLaunchKernelGGL((gemm_bf16<2, 0>), dim3(MTOT / 128, 3072 / 128), dim3(256), 0, stream,
                       xb, wc, bq, bk, bv, qws, kws, vws, (float*)nullptr);

    hipLaunchKernelGGL(attn_kernel, dim3(SEQ / 128, BATCH * NHEAD), dim3(512), 0, stream,
                       qws, kws, vws, aws);

    hipLaunchKernelGGL((gemm_bf16<1, 1>), dim3(MTOT / 64, DMODEL / 128), dim3(256), 0, stream,
                       aws, wob, bo, (const float*)nullptr, (const float*)nullptr,
                       (ushort*)nullptr, (ushort*)nullptr, (ushort*)nullptr, (float*)d_out);
}